// Round 1
// baseline (84.812 us; speedup 1.0000x reference)
//
#include <hip/hip_runtime.h>
#include <stdint.h>

#define HASH_T 524288u
#define HASH_MASK (HASH_T - 1u)
#define PRIME1 2654435761u
#define PRIME2 805459861u

// Output: [B][32][256][256] f32, channel c = 2*l + f.
// Thread = one (b, i, j) pixel; inner loop over 16 levels.
__global__ __launch_bounds__(256) void lia_hashgrid_kernel(
    const float* __restrict__ x0,        // [B]
    const float* __restrict__ y0,        // [B]
    const float* __restrict__ tables,    // [T][2]
    const uint32_t* __restrict__ seeds,  // [16]
    const float* __restrict__ level_N,   // [16]
    const int* __restrict__ tile_p,      // scalar
    float* __restrict__ out)             // [B][32][65536]
{
    const int gid = blockIdx.x * 256 + threadIdx.x;
    const int j = gid & 255;
    const int i = (gid >> 8) & 255;
    const int b = gid >> 16;

    const float inv_tile = 1.0f / (float)(*tile_p);   // 1/1024, exact
    const float px = (float)j + x0[b];
    const float py = (float)i + y0[b];

    float* outp = out + (size_t)b * 32u * 65536u + (size_t)(i * 256 + j);

    #pragma unroll 4
    for (int l = 0; l < 16; ++l) {
        const float scale = level_N[l] * inv_tile;
        const uint32_t seed = seeds[l];

        const float xn = px * scale;
        const float yn = py * scale;
        const float flx = floorf(xn);
        const float fly = floorf(yn);
        const float fx = xn - flx;
        const float fy = yn - fly;
        const uint32_t ix0 = (uint32_t)(int)flx;
        const uint32_t iy0 = (uint32_t)(int)fly;
        const uint32_t ix1 = ix0 + 1u;
        const uint32_t iy1 = iy0 + 1u;

        const uint32_t hx0 = ix0 * PRIME1;
        const uint32_t hx1 = ix1 * PRIME1;
        const uint32_t hy0 = iy0 * PRIME2;
        const uint32_t hy1 = iy1 * PRIME2;

        const uint32_t h00 = (hx0 ^ hy0 ^ seed) & HASH_MASK;
        const uint32_t h10 = (hx1 ^ hy0 ^ seed) & HASH_MASK;
        const uint32_t h01 = (hx0 ^ hy1 ^ seed) & HASH_MASK;
        const uint32_t h11 = (hx1 ^ hy1 ^ seed) & HASH_MASK;

        const float2 f00 = *(const float2*)(tables + 2u * h00);
        const float2 f10 = *(const float2*)(tables + 2u * h10);
        const float2 f01 = *(const float2*)(tables + 2u * h01);
        const float2 f11 = *(const float2*)(tables + 2u * h11);

        const float gx = 1.0f - fx;
        const float gy = 1.0f - fy;
        const float w00 = gx * gy;
        const float w10 = fx * gy;
        const float w01 = gx * fy;
        const float w11 = fx * fy;

        const float e0 = w00 * f00.x + w10 * f10.x + w01 * f01.x + w11 * f11.x;
        const float e1 = w00 * f00.y + w10 * f10.y + w01 * f01.y + w11 * f11.y;

        outp[(size_t)(2 * l) * 65536u]     = e0;
        outp[(size_t)(2 * l + 1) * 65536u] = e1;
    }
}

extern "C" void kernel_launch(void* const* d_in, const int* in_sizes, int n_in,
                              void* d_out, int out_size, void* d_ws, size_t ws_size,
                              hipStream_t stream) {
    const float*    x0      = (const float*)d_in[0];
    const float*    y0      = (const float*)d_in[1];
    const float*    tables  = (const float*)d_in[2];
    const uint32_t* seeds   = (const uint32_t*)d_in[3];
    const float*    level_N = (const float*)d_in[4];
    const int*      tile_p  = (const int*)d_in[6];   // complete_tile_size
    float*          out     = (float*)d_out;

    const int B = in_sizes[0];           // 8
    const int n_threads = B * 256 * 256; // one thread per pixel
    const int n_blocks = n_threads / 256;

    lia_hashgrid_kernel<<<n_blocks, 256, 0, stream>>>(
        x0, y0, tables, seeds, level_N, tile_p, out);
}

// Round 2
// 70.992 us; speedup vs baseline: 1.1947x; 1.1947x over previous
//
#include <hip/hip_runtime.h>
#include <stdint.h>

#define HASH_T 524288u
#define HASH_MASK (HASH_T - 1u)
#define PRIME1 2654435761u
#define PRIME2 805459861u

// Output: [B][32][256][256] f32, channel c = 2*l + f.
// Thread = one (b, i, j) pixel for HALF the levels (8 levels each).
// half=0 -> levels 0..7 (channels 0..15), half=1 -> levels 8..15 (channels 16..31).
// Full unroll over 8 levels => ~32 independent gathers in flight per thread.
__global__ __launch_bounds__(256) void lia_hashgrid_kernel(
    const float* __restrict__ x0,        // [B]
    const float* __restrict__ y0,        // [B]
    const float* __restrict__ tables,    // [T][2]
    const uint32_t* __restrict__ seeds,  // [16]
    const float* __restrict__ level_N,   // [16]
    const int* __restrict__ tile_p,      // scalar
    float* __restrict__ out)             // [B][32][65536]
{
    const int gid = blockIdx.x * 256 + threadIdx.x;
    const int j = gid & 255;
    const int i = (gid >> 8) & 255;
    const int bh = gid >> 16;           // wave-uniform
    const int half = bh & 1;
    const int b = bh >> 1;

    const float inv_tile = 1.0f / (float)(*tile_p);   // 1/1024, exact
    const float px = (float)j + x0[b];
    const float py = (float)i + y0[b];

    const float2* __restrict__ tab2 = (const float2*)tables;
    float* outp = out + ((size_t)b * 32u + (size_t)half * 16u) * 65536u
                      + (size_t)(i * 256 + j);

    const int lbase = half * 8;         // wave-uniform -> scalar loads below

    #pragma unroll
    for (int ll = 0; ll < 8; ++ll) {
        const int l = lbase + ll;
        const float scale = level_N[l] * inv_tile;
        const uint32_t seed = seeds[l];

        const float xn = px * scale;
        const float yn = py * scale;
        const float flx = floorf(xn);
        const float fly = floorf(yn);
        const float fx = xn - flx;
        const float fy = yn - fly;
        const uint32_t ix0 = (uint32_t)(int)flx;
        const uint32_t iy0 = (uint32_t)(int)fly;

        const uint32_t hx0 = ix0 * PRIME1;
        const uint32_t hx1 = hx0 + PRIME1;      // (ix0+1)*P1
        const uint32_t hy0 = iy0 * PRIME2;
        const uint32_t hy1 = hy0 + PRIME2;      // (iy0+1)*P2

        const uint32_t h00 = (hx0 ^ hy0 ^ seed) & HASH_MASK;
        const uint32_t h10 = (hx1 ^ hy0 ^ seed) & HASH_MASK;
        const uint32_t h01 = (hx0 ^ hy1 ^ seed) & HASH_MASK;
        const uint32_t h11 = (hx1 ^ hy1 ^ seed) & HASH_MASK;

        const float2 f00 = tab2[h00];
        const float2 f10 = tab2[h10];
        const float2 f01 = tab2[h01];
        const float2 f11 = tab2[h11];

        const float gx = 1.0f - fx;
        const float gy = 1.0f - fy;
        const float w00 = gx * gy;
        const float w10 = fx * gy;
        const float w01 = gx * fy;
        const float w11 = fx * fy;

        const float e0 = w00 * f00.x + w10 * f10.x + w01 * f01.x + w11 * f11.x;
        const float e1 = w00 * f00.y + w10 * f10.y + w01 * f01.y + w11 * f11.y;

        __builtin_nontemporal_store(e0, &outp[(size_t)(2 * ll) * 65536u]);
        __builtin_nontemporal_store(e1, &outp[(size_t)(2 * ll + 1) * 65536u]);
    }
}

extern "C" void kernel_launch(void* const* d_in, const int* in_sizes, int n_in,
                              void* d_out, int out_size, void* d_ws, size_t ws_size,
                              hipStream_t stream) {
    const float*    x0      = (const float*)d_in[0];
    const float*    y0      = (const float*)d_in[1];
    const float*    tables  = (const float*)d_in[2];
    const uint32_t* seeds   = (const uint32_t*)d_in[3];
    const float*    level_N = (const float*)d_in[4];
    const int*      tile_p  = (const int*)d_in[6];   // complete_tile_size
    float*          out     = (float*)d_out;

    const int B = in_sizes[0];                 // 8
    const int n_threads = B * 2 * 256 * 256;   // 2 threads per pixel (8 levels each)
    const int n_blocks = n_threads / 256;

    lia_hashgrid_kernel<<<n_blocks, 256, 0, stream>>>(
        x0, y0, tables, seeds, level_N, tile_p, out);
}